// Round 1
// baseline (743.485 us; speedup 1.0000x reference)
//
#include <hip/hip_runtime.h>
#include <math.h>

#define Bn 8
#define Tn 2048
#define Cn 1024
#define Hn 64
#define BTH ((size_t)Bn * Tn * Hn)

// ---------------------------------------------------------------------------
// Projection: xh[b,t,h] = sum_c x[b,t,c] * W[h,c]
// grid (512, 3): y selects (k,Wk)->kh, (q,Wq)->qh, (v,Wv)->vh
// block 256 = 4 waves; each wave handles 8 rows, lane = h (0..63).
// W tile staged in LDS (stride 258 floats: b64-aligned, 2-way-free reads).
// X read via wave-uniform addresses (scalar path / broadcast).
// ---------------------------------------------------------------------------
__global__ __launch_bounds__(256) void proj_kernel(
    const float* __restrict__ k, const float* __restrict__ q,
    const float* __restrict__ v,
    const float* __restrict__ Wk, const float* __restrict__ Wq,
    const float* __restrict__ Wv,
    float* __restrict__ ws)
{
    const int which = blockIdx.y;
    const float* X = (which == 0) ? k : (which == 1) ? q : v;
    const float* W = (which == 0) ? Wk : (which == 1) ? Wq : Wv;
    float* O = ws + (size_t)which * BTH;

    __shared__ float Ws[Hn][258];   // [h][256 c-tile + pad2]

    const int tid  = threadIdx.x;
    const int lane = tid & 63;                       // = h
    int wv = __builtin_amdgcn_readfirstlane(tid >> 6);
    const int row0 = blockIdx.x * 32 + wv * 8;

    float acc[8];
#pragma unroll
    for (int i = 0; i < 8; ++i) acc[i] = 0.f;

    const float4* wsrc = (const float4*)W;           // W row = 256 float4s

    for (int ct = 0; ct < 4; ++ct) {
        __syncthreads();
        // stage W[:, ct*256 .. ct*256+255]: 16384 floats, 64 f4 per thread
#pragma unroll
        for (int u = 0; u < 16; ++u) {
            int if4 = tid + 256 * u;                 // 0..4095
            int hh  = if4 >> 6;                      // 0..63
            int c4  = if4 & 63;                      // 0..63
            float4 w4 = wsrc[(size_t)hh * 256 + ct * 64 + c4];
            float2* dst = (float2*)&Ws[hh][c4 * 4];
            dst[0] = make_float2(w4.x, w4.y);
            dst[1] = make_float2(w4.z, w4.w);
        }
        __syncthreads();

        const float2* Wrow = (const float2*)&Ws[lane][0];
#pragma unroll 4
        for (int c4 = 0; c4 < 64; ++c4) {
            float2 wa = Wrow[2 * c4];
            float2 wb = Wrow[2 * c4 + 1];
#pragma unroll
            for (int i = 0; i < 8; ++i) {
                const float4 x4 = *(const float4*)(X + (size_t)(row0 + i) * Cn
                                                     + ct * 256 + c4 * 4);
                acc[i] += wa.x * x4.x + wa.y * x4.y + wb.x * x4.z + wb.y * x4.w;
            }
        }
    }

#pragma unroll
    for (int i = 0; i < 8; ++i)
        O[(size_t)(row0 + i) * Hn + lane] = acc[i];
}

// ---------------------------------------------------------------------------
// Flash-style attention over projected heads.
// grid (32, 8); block 256. Each block handles q-tiles bx and 63-bx (32 rows
// each) -> uniform 33 k-tiles per block across the causal triangle.
// thread: r = tid>>3 (q-row in tile), oct = tid&7 (8 score-cols / 8 out-dims).
// ---------------------------------------------------------------------------
__global__ __launch_bounds__(256) void attn_kernel(
    const float* __restrict__ ws,
    const int* __restrict__ mask,
    float* __restrict__ out)
{
    const float* kh = ws;
    const float* qh = ws + BTH;
    const float* vh = ws + 2 * BTH;

    const int b   = blockIdx.y;
    const int bx  = blockIdx.x;
    const int tid = threadIdx.x;
    const int r   = tid >> 3;     // 0..31
    const int oct = tid & 7;      // 0..7

    __shared__ float Ks[64][68];
    __shared__ float Vs[64][68];
    __shared__ float Ps[32][68];
    __shared__ int   Msk[64];

    for (int half = 0; half < 2; ++half) {
        const int qt   = half ? (63 - bx) : bx;
        const int qrow = qt * 32 + r;

        // Q row -> registers (64 floats)
        float4 qreg[16];
        const float4* qsrc = (const float4*)(qh + ((size_t)b * Tn + qrow) * Hn);
#pragma unroll
        for (int d4 = 0; d4 < 16; ++d4) qreg[d4] = qsrc[d4];

        float o[8];
#pragma unroll
        for (int i = 0; i < 8; ++i) o[i] = 0.f;
        float m = -1e30f, l = 0.f;

        const int jmax = (qt * 32 + 31) >> 6;
        for (int j = 0; j <= jmax; ++j) {
            __syncthreads();   // protect LDS from previous iteration's readers
            // stage K/V tiles: rows j*64 .. j*64+63, contiguous 1024 float4s
            {
                const float4* ksrc =
                    (const float4*)(kh + ((size_t)b * Tn + j * 64) * Hn);
                const float4* vsrc =
                    (const float4*)(vh + ((size_t)b * Tn + j * 64) * Hn);
#pragma unroll
                for (int u = 0; u < 4; ++u) {
                    int if4 = tid + 256 * u;
                    int row = if4 >> 4, c4 = if4 & 15;
                    *(float4*)&Ks[row][c4 * 4] = ksrc[if4];
                    *(float4*)&Vs[row][c4 * 4] = vsrc[if4];
                }
                if (tid < 64) Msk[tid] = mask[(size_t)b * Tn + j * 64 + tid];
            }
            __syncthreads();

            // scores: 8 cols per thread (c = i*8 + oct)
            float p[8];
            float mt = -1e30f;
#pragma unroll
            for (int i = 0; i < 8; ++i) {
                const int c = i * 8 + oct;
                float s = 0.f;
                const float* krow = &Ks[c][0];
#pragma unroll
                for (int d4 = 0; d4 < 16; ++d4) {
                    float4 k4 = *(const float4*)(krow + d4 * 4);
                    s += qreg[d4].x * k4.x + qreg[d4].y * k4.y
                       + qreg[d4].z * k4.z + qreg[d4].w * k4.w;
                }
                s *= 0.125f;   // 1/sqrt(64)
                const bool valid = (j * 64 + c <= qrow) && (Msk[c] != 0);
                s = valid ? s : -1e30f;
                p[i] = s;
                mt = fmaxf(mt, s);
            }
            // row max over the 8 lanes of this row
            mt = fmaxf(mt, __shfl_xor(mt, 1, 8));
            mt = fmaxf(mt, __shfl_xor(mt, 2, 8));
            mt = fmaxf(mt, __shfl_xor(mt, 4, 8));

            const float m_new = fmaxf(m, mt);
            const float alpha = __expf(m - m_new);   // first tile: exp(-huge)=0

            float psum = 0.f;
#pragma unroll
            for (int i = 0; i < 8; ++i) {
                float pv = (p[i] <= -1e29f) ? 0.f : __expf(p[i] - m_new);
                p[i] = pv;
                psum += pv;
            }
            psum += __shfl_xor(psum, 1, 8);
            psum += __shfl_xor(psum, 2, 8);
            psum += __shfl_xor(psum, 4, 8);

            l = l * alpha + psum;
            m = m_new;
#pragma unroll
            for (int i = 0; i < 8; ++i) o[i] *= alpha;

#pragma unroll
            for (int i = 0; i < 8; ++i) Ps[r][i * 8 + oct] = p[i];
            __syncthreads();

            // O += P * V   (thread owns dims oct*8 .. oct*8+7)
#pragma unroll 4
            for (int kk = 0; kk < 64; ++kk) {
                const float pk = Ps[r][kk];
                const float4 v0 = *(const float4*)&Vs[kk][oct * 8];
                const float4 v1 = *(const float4*)&Vs[kk][oct * 8 + 4];
                o[0] += pk * v0.x; o[1] += pk * v0.y;
                o[2] += pk * v0.z; o[3] += pk * v0.w;
                o[4] += pk * v1.x; o[5] += pk * v1.y;
                o[6] += pk * v1.z; o[7] += pk * v1.w;
            }
        }

        const float inv = 1.0f / l;   // l>0 for all-ones key mask
        float4 r0 = make_float4(o[0] * inv, o[1] * inv, o[2] * inv, o[3] * inv);
        float4 r1 = make_float4(o[4] * inv, o[5] * inv, o[6] * inv, o[7] * inv);
        float4* dst = (float4*)(out + ((size_t)b * Tn + qrow) * Hn + oct * 8);
        dst[0] = r0;
        dst[1] = r1;
        __syncthreads();   // before next half re-stages LDS
    }
}

extern "C" void kernel_launch(void* const* d_in, const int* in_sizes, int n_in,
                              void* d_out, int out_size, void* d_ws, size_t ws_size,
                              hipStream_t stream)
{
    const float* k    = (const float*)d_in[0];
    const float* q    = (const float*)d_in[1];
    const float* v    = (const float*)d_in[2];
    const int*   mask = (const int*)d_in[3];
    const float* Wk   = (const float*)d_in[4];
    const float* Wq   = (const float*)d_in[5];
    const float* Wv   = (const float*)d_in[6];
    float* out = (float*)d_out;
    float* ws  = (float*)d_ws;   // kh | qh | vh, each B*T*H fp32 (12.6 MB)

    dim3 pb(256), pg(Bn * Tn / 32, 3);
    proj_kernel<<<pg, pb, 0, stream>>>(k, q, v, Wk, Wq, Wv, ws);

    dim3 ab(256), ag(Tn / 64, Bn);
    attn_kernel<<<ag, ab, 0, stream>>>(ws, mask, out);
}

// Round 2
// 445.175 us; speedup vs baseline: 1.6701x; 1.6701x over previous
//
#include <hip/hip_runtime.h>
#include <math.h>

#define Bn 8
#define Tn 2048
#define Cn 1024
#define Hn 64
#define BTH ((size_t)Bn * Tn * Hn)

typedef __attribute__((ext_vector_type(8))) short bf16x8;
typedef __attribute__((ext_vector_type(4))) float f32x4;

static __device__ __forceinline__ unsigned short bf16rne(float f) {
    union { float f; unsigned u; } x; x.f = f;
    unsigned u = x.u;
    return (unsigned short)((u + 0x7FFFu + ((u >> 16) & 1u)) >> 16);
}

// ---------------------------------------------------------------------------
// MFMA projection: O[row,h] = sum_c X[row,c] * W[h,c]   (B^T-form GEMM)
// grid (256, 3); block 256 = 4 waves. Block = 64 rows x 64 h, K-chunks of 64
// staged fp32->bf16 in LDS (stride 72 ushorts -> only 2-way bank aliasing).
// Wave w owns rows [w*16, w*16+16), four 16x16 h-tiles, 16x16x32 bf16 MFMA.
// ---------------------------------------------------------------------------
__global__ __launch_bounds__(256) void proj_kernel(
    const float* __restrict__ k, const float* __restrict__ q,
    const float* __restrict__ v,
    const float* __restrict__ Wk, const float* __restrict__ Wq,
    const float* __restrict__ Wv,
    float* __restrict__ ws)
{
    const int which = blockIdx.y;
    const float* X = (which == 0) ? k : (which == 1) ? q : v;
    const float* W = (which == 0) ? Wk : (which == 1) ? Wq : Wv;
    float* O = ws + (size_t)which * BTH;

    __shared__ unsigned short Xs[64][72];
    __shared__ unsigned short Wt[64][72];

    const int tid  = threadIdx.x;
    const int wave = __builtin_amdgcn_readfirstlane(tid >> 6);
    const int lane = tid & 63;
    const int m    = lane & 15;      // row/col within 16x16 tile
    const int quad = lane >> 4;      // 0..3
    const int row0 = blockIdx.x * 64;

    f32x4 acc[4];
#pragma unroll
    for (int t = 0; t < 4; ++t) acc[t] = (f32x4){0.f, 0.f, 0.f, 0.f};

    for (int ct = 0; ct < 16; ++ct) {
        __syncthreads();
        // stage X[64 rows][64 c] and W[64 h][64 c] as bf16
#pragma unroll
        for (int u = 0; u < 4; ++u) {
            const int if4 = tid + 256 * u;      // 0..1023
            const int row = if4 >> 4;           // 0..63
            const int c4  = if4 & 15;           // 0..15
            const float4 xv = *(const float4*)(X + (size_t)(row0 + row) * Cn
                                                 + ct * 64 + c4 * 4);
            const float4 wv = *(const float4*)(W + (size_t)row * Cn
                                                 + ct * 64 + c4 * 4);
            ushort4 xb, wb;
            xb.x = bf16rne(xv.x); xb.y = bf16rne(xv.y);
            xb.z = bf16rne(xv.z); xb.w = bf16rne(xv.w);
            wb.x = bf16rne(wv.x); wb.y = bf16rne(wv.y);
            wb.z = bf16rne(wv.z); wb.w = bf16rne(wv.w);
            *(ushort4*)&Xs[row][c4 * 4] = xb;
            *(ushort4*)&Wt[row][c4 * 4] = wb;
        }
        __syncthreads();

#pragma unroll
        for (int kc = 0; kc < 64; kc += 32) {
            const bf16x8 a = *(const bf16x8*)&Xs[wave * 16 + m][kc + quad * 8];
#pragma unroll
            for (int ht = 0; ht < 4; ++ht) {
                const bf16x8 bfr =
                    *(const bf16x8*)&Wt[ht * 16 + m][kc + quad * 8];
                acc[ht] = __builtin_amdgcn_mfma_f32_16x16x32_bf16(
                    a, bfr, acc[ht], 0, 0, 0);
            }
        }
    }

    // epilogue: D layout col=lane&15, row=quad*4+reg
#pragma unroll
    for (int ht = 0; ht < 4; ++ht)
#pragma unroll
        for (int r = 0; r < 4; ++r)
            O[(size_t)(row0 + wave * 16 + quad * 4 + r) * Hn + ht * 16 + m] =
                acc[ht][r];
}

// ---------------------------------------------------------------------------
// Flash-style attention over projected heads (unchanged from R0).
// grid (32, 8); block 256. Each block handles q-tiles bx and 63-bx.
// ---------------------------------------------------------------------------
__global__ __launch_bounds__(256) void attn_kernel(
    const float* __restrict__ ws,
    const int* __restrict__ mask,
    float* __restrict__ out)
{
    const float* kh = ws;
    const float* qh = ws + BTH;
    const float* vh = ws + 2 * BTH;

    const int b   = blockIdx.y;
    const int bx  = blockIdx.x;
    const int tid = threadIdx.x;
    const int r   = tid >> 3;     // 0..31
    const int oct = tid & 7;      // 0..7

    __shared__ float Ks[64][68];
    __shared__ float Vs[64][68];
    __shared__ float Ps[32][68];
    __shared__ int   Msk[64];

    for (int half = 0; half < 2; ++half) {
        const int qt   = half ? (63 - bx) : bx;
        const int qrow = qt * 32 + r;

        float4 qreg[16];
        const float4* qsrc = (const float4*)(qh + ((size_t)b * Tn + qrow) * Hn);
#pragma unroll
        for (int d4 = 0; d4 < 16; ++d4) qreg[d4] = qsrc[d4];

        float o[8];
#pragma unroll
        for (int i = 0; i < 8; ++i) o[i] = 0.f;
        float m = -1e30f, l = 0.f;

        const int jmax = (qt * 32 + 31) >> 6;
        for (int j = 0; j <= jmax; ++j) {
            __syncthreads();
            {
                const float4* ksrc =
                    (const float4*)(kh + ((size_t)b * Tn + j * 64) * Hn);
                const float4* vsrc =
                    (const float4*)(vh + ((size_t)b * Tn + j * 64) * Hn);
#pragma unroll
                for (int u = 0; u < 4; ++u) {
                    int if4 = tid + 256 * u;
                    int row = if4 >> 4, c4 = if4 & 15;
                    *(float4*)&Ks[row][c4 * 4] = ksrc[if4];
                    *(float4*)&Vs[row][c4 * 4] = vsrc[if4];
                }
                if (tid < 64) Msk[tid] = mask[(size_t)b * Tn + j * 64 + tid];
            }
            __syncthreads();

            float p[8];
            float mt = -1e30f;
#pragma unroll
            for (int i = 0; i < 8; ++i) {
                const int c = i * 8 + oct;
                float s = 0.f;
                const float* krow = &Ks[c][0];
#pragma unroll
                for (int d4 = 0; d4 < 16; ++d4) {
                    float4 k4 = *(const float4*)(krow + d4 * 4);
                    s += qreg[d4].x * k4.x + qreg[d4].y * k4.y
                       + qreg[d4].z * k4.z + qreg[d4].w * k4.w;
                }
                s *= 0.125f;
                const bool valid = (j * 64 + c <= qrow) && (Msk[c] != 0);
                s = valid ? s : -1e30f;
                p[i] = s;
                mt = fmaxf(mt, s);
            }
            mt = fmaxf(mt, __shfl_xor(mt, 1, 8));
            mt = fmaxf(mt, __shfl_xor(mt, 2, 8));
            mt = fmaxf(mt, __shfl_xor(mt, 4, 8));

            const float m_new = fmaxf(m, mt);
            const float alpha = __expf(m - m_new);

            float psum = 0.f;
#pragma unroll
            for (int i = 0; i < 8; ++i) {
                float pv = (p[i] <= -1e29f) ? 0.f : __expf(p[i] - m_new);
                p[i] = pv;
                psum += pv;
            }
            psum += __shfl_xor(psum, 1, 8);
            psum += __shfl_xor(psum, 2, 8);
            psum += __shfl_xor(psum, 4, 8);

            l = l * alpha + psum;
            m = m_new;
#pragma unroll
            for (int i = 0; i < 8; ++i) o[i] *= alpha;

#pragma unroll
            for (int i = 0; i < 8; ++i) Ps[r][i * 8 + oct] = p[i];
            __syncthreads();

#pragma unroll 4
            for (int kk = 0; kk < 64; ++kk) {
                const float pk = Ps[r][kk];
                const float4 v0 = *(const float4*)&Vs[kk][oct * 8];
                const float4 v1 = *(const float4*)&Vs[kk][oct * 8 + 4];
                o[0] += pk * v0.x; o[1] += pk * v0.y;
                o[2] += pk * v0.z; o[3] += pk * v0.w;
                o[4] += pk * v1.x; o[5] += pk * v1.y;
                o[6] += pk * v1.z; o[7] += pk * v1.w;
            }
        }

        const float inv = 1.0f / l;
        float4 r0 = make_float4(o[0] * inv, o[1] * inv, o[2] * inv, o[3] * inv);
        float4 r1 = make_float4(o[4] * inv, o[5] * inv, o[6] * inv, o[7] * inv);
        float4* dst = (float4*)(out + ((size_t)b * Tn + qrow) * Hn + oct * 8);
        dst[0] = r0;
        dst[1] = r1;
        __syncthreads();
    }
}

extern "C" void kernel_launch(void* const* d_in, const int* in_sizes, int n_in,
                              void* d_out, int out_size, void* d_ws, size_t ws_size,
                              hipStream_t stream)
{
    const float* k    = (const float*)d_in[0];
    const float* q    = (const float*)d_in[1];
    const float* v    = (const float*)d_in[2];
    const int*   mask = (const int*)d_in[3];
    const float* Wk   = (const float*)d_in[4];
    const float* Wq   = (const float*)d_in[5];
    const float* Wv   = (const float*)d_in[6];
    float* out = (float*)d_out;
    float* ws  = (float*)d_ws;   // kh | qh | vh, each B*T*H fp32

    dim3 pb(256), pg(Bn * Tn / 64, 3);
    proj_kernel<<<pg, pb, 0, stream>>>(k, q, v, Wk, Wq, Wv, ws);

    dim3 ab(256), ag(Tn / 64, Bn);
    attn_kernel<<<ag, ab, 0, stream>>>(ws, mask, out);
}

// Round 3
// 279.689 us; speedup vs baseline: 2.6583x; 1.5917x over previous
//
#include <hip/hip_runtime.h>
#include <hip/hip_bf16.h>
#include <math.h>

#define Bn 8
#define Tn 2048
#define Cn 1024
#define Hn 64
#define BTHb ((size_t)Bn * Tn * Hn)   // elements per projected matrix (bf16)

typedef __attribute__((ext_vector_type(8))) short bf16x8;
typedef __attribute__((ext_vector_type(4))) float f32x4;

static __device__ __forceinline__ unsigned short bf16rne(float f) {
    union { float f; unsigned u; } x; x.f = f;
    return (unsigned short)((x.u + 0x7FFFu + ((x.u >> 16) & 1u)) >> 16);
}

// ---------------------------------------------------------------------------
// MFMA projection -> bf16 output: O[row,h] = sum_c X[row,c] * W[h,c]
// grid (256, 3); block 256 = 4 waves; 64 rows x 64 h per block.
// K-chunks of 64 staged fp32->bf16 in LDS; next chunk's global loads are
// issued right after the stage barrier so HBM latency overlaps the MFMAs.
// ---------------------------------------------------------------------------
__global__ __launch_bounds__(256) void proj_kernel(
    const float* __restrict__ k, const float* __restrict__ q,
    const float* __restrict__ v,
    const float* __restrict__ Wk, const float* __restrict__ Wq,
    const float* __restrict__ Wv,
    unsigned short* __restrict__ ws)
{
    const int which = blockIdx.y;
    const float* X = (which == 0) ? k : (which == 1) ? q : v;
    const float* W = (which == 0) ? Wk : (which == 1) ? Wq : Wv;
    unsigned short* O = ws + (size_t)which * BTHb;

    __shared__ unsigned short Xs[64][72];
    __shared__ unsigned short Wt[64][72];

    const int tid  = threadIdx.x;
    const int wave = __builtin_amdgcn_readfirstlane(tid >> 6);
    const int lane = tid & 63;
    const int m    = lane & 15;
    const int quad = lane >> 4;
    const int row0 = blockIdx.x * 64;

    const int srow = tid >> 4;          // 0..15 step over 4 rows? no: 0..15
    const int sc4  = tid & 15;          // float4 index within 64-col chunk

    f32x4 acc[4];
#pragma unroll
    for (int t = 0; t < 4; ++t) acc[t] = (f32x4){0.f, 0.f, 0.f, 0.f};

    float4 xr[4], wr[4];
    // prefetch chunk 0: thread covers rows {srow, srow+16, srow+32, srow+48}
#pragma unroll
    for (int u = 0; u < 4; ++u) {
        const int row = srow + 16 * u;
        xr[u] = *(const float4*)(X + (size_t)(row0 + row) * Cn + sc4 * 4);
        wr[u] = *(const float4*)(W + (size_t)row * Cn + sc4 * 4);
    }

    for (int ct = 0; ct < 16; ++ct) {
        __syncthreads();
#pragma unroll
        for (int u = 0; u < 4; ++u) {
            const int row = srow + 16 * u;
            ushort4 xb, wb;
            xb.x = bf16rne(xr[u].x); xb.y = bf16rne(xr[u].y);
            xb.z = bf16rne(xr[u].z); xb.w = bf16rne(xr[u].w);
            wb.x = bf16rne(wr[u].x); wb.y = bf16rne(wr[u].y);
            wb.z = bf16rne(wr[u].z); wb.w = bf16rne(wr[u].w);
            *(ushort4*)&Xs[row][sc4 * 4] = xb;
            *(ushort4*)&Wt[row][sc4 * 4] = wb;
        }
        __syncthreads();

        if (ct < 15) {
#pragma unroll
            for (int u = 0; u < 4; ++u) {
                const int row = srow + 16 * u;
                xr[u] = *(const float4*)(X + (size_t)(row0 + row) * Cn
                                           + (ct + 1) * 64 + sc4 * 4);
                wr[u] = *(const float4*)(W + (size_t)row * Cn
                                           + (ct + 1) * 64 + sc4 * 4);
            }
        }

#pragma unroll
        for (int kc = 0; kc < 64; kc += 32) {
            const bf16x8 a = *(const bf16x8*)&Xs[wave * 16 + m][kc + quad * 8];
#pragma unroll
            for (int ht = 0; ht < 4; ++ht) {
                const bf16x8 bfr =
                    *(const bf16x8*)&Wt[ht * 16 + m][kc + quad * 8];
                acc[ht] = __builtin_amdgcn_mfma_f32_16x16x32_bf16(
                    a, bfr, acc[ht], 0, 0, 0);
            }
        }
    }

    // D layout: col=lane&15, row=quad*4+reg
#pragma unroll
    for (int ht = 0; ht < 4; ++ht)
#pragma unroll
        for (int r = 0; r < 4; ++r)
            O[(size_t)(row0 + wave * 16 + quad * 4 + r) * Hn + ht * 16 + m] =
                bf16rne(acc[ht][r]);
}

// ---------------------------------------------------------------------------
// MFMA flash attention. grid (32, 8); block 256 = 4 waves.
// Block bx = q-tile of 64 rows (qt*64..+64); wave w owns rows wrb..wrb+16.
// k-loop j = 0..qt over 64-key tiles: stage K (row-major) + V^T (dim-major)
// bf16 in LDS, QK^T via 16x16x32 MFMA (4 col-tiles x 2 k-chunks), online
// softmax in C-layout registers, P -> LDS (bf16) -> A-frag, PV via MFMA.
// Wall time set by the deepest blocks (qt=31 -> 32 tiles) = same as a
// uniform pairing, since grid == 256 == #CUs (1 block/CU).
// ---------------------------------------------------------------------------
__global__ __launch_bounds__(256) void attn_kernel(
    const unsigned short* __restrict__ ws,
    const int* __restrict__ mask,
    float* __restrict__ out)
{
    const unsigned short* kh = ws;
    const unsigned short* qh = ws + BTHb;
    const unsigned short* vh = ws + 2 * BTHb;

    const int b   = blockIdx.y;
    const int qt  = blockIdx.x;
    const int tid = threadIdx.x;
    const int wave = __builtin_amdgcn_readfirstlane(tid >> 6);
    const int lane = tid & 63;
    const int ln   = lane & 15;
    const int quad = lane >> 4;

    __shared__ unsigned short Ks[64][72];   // [kpos][dim]
    __shared__ unsigned short Vt[64][72];   // [dim][kpos]
    __shared__ unsigned short Ps[64][72];   // [q-row local][kpos]
    __shared__ int Msk[64];

    const int wrb = qt * 64 + wave * 16;    // wave's first q-row

    // Q A-frags: A[m=ln][k=quad*8+j], 2 chunks of K=32
    bf16x8 qa[2];
#pragma unroll
    for (int kc = 0; kc < 2; ++kc)
        qa[kc] = *(const bf16x8*)(qh + ((size_t)b * Tn + wrb + ln) * Hn
                                     + kc * 32 + quad * 8);

    f32x4 oacc[4];
#pragma unroll
    for (int t = 0; t < 4; ++t) oacc[t] = (f32x4){0.f, 0.f, 0.f, 0.f};
    float mrow[4] = {-1e30f, -1e30f, -1e30f, -1e30f};
    float lrow[4] = {0.f, 0.f, 0.f, 0.f};

    // staging: K by (row=tid>>2, seg=tid&3)  [coalesced global, b128 LDS]
    //          V by (col=tid&63, seg=tid>>6) [conflict-free transpose writes]
    const int krow = tid >> 2, kseg = tid & 3;
    const int vcol = tid & 63, vseg = tid >> 6;

    uint4 kreg[2], vreg[2];
    int mreg = 0;
    {
        const unsigned short* kp =
            kh + ((size_t)b * Tn + krow) * Hn + kseg * 16;
        kreg[0] = *(const uint4*)kp;
        kreg[1] = *(const uint4*)(kp + 8);
        const unsigned short* vp =
            vh + ((size_t)b * Tn + vcol) * Hn + vseg * 16;
        vreg[0] = *(const uint4*)vp;
        vreg[1] = *(const uint4*)(vp + 8);
        if (tid < 64) mreg = mask[(size_t)b * Tn + tid];
    }

    for (int j = 0; j <= qt; ++j) {
        __syncthreads();   // previous tile's LDS readers done
        *(uint4*)&Ks[krow][kseg * 16]     = kreg[0];
        *(uint4*)&Ks[krow][kseg * 16 + 8] = kreg[1];
        {
            const unsigned short* vs = (const unsigned short*)vreg;
#pragma unroll
            for (int jj = 0; jj < 16; ++jj)
                Vt[vseg * 16 + jj][vcol] = vs[jj];
        }
        if (tid < 64) Msk[tid] = mreg;
        __syncthreads();   // staged tile visible

        if (j < qt) {      // prefetch next tile; latency overlaps compute
            const unsigned short* kp =
                kh + ((size_t)b * Tn + (j + 1) * 64 + krow) * Hn + kseg * 16;
            kreg[0] = *(const uint4*)kp;
            kreg[1] = *(const uint4*)(kp + 8);
            const unsigned short* vp =
                vh + ((size_t)b * Tn + (j + 1) * 64 + vcol) * Hn + vseg * 16;
            vreg[0] = *(const uint4*)vp;
            vreg[1] = *(const uint4*)(vp + 8);
            if (tid < 64) mreg = mask[(size_t)b * Tn + (j + 1) * 64 + tid];
        }

        // ---- S = Q K^T : 4 col-tiles (16 kpos each) x 2 K-chunks ----
        f32x4 sacc[4];
#pragma unroll
        for (int t = 0; t < 4; ++t) sacc[t] = (f32x4){0.f, 0.f, 0.f, 0.f};
#pragma unroll
        for (int kc = 0; kc < 2; ++kc) {
#pragma unroll
            for (int nt = 0; nt < 4; ++nt) {
                const bf16x8 kb =
                    *(const bf16x8*)&Ks[nt * 16 + ln][kc * 32 + quad * 8];
                sacc[nt] = __builtin_amdgcn_mfma_f32_16x16x32_bf16(
                    qa[kc], kb, sacc[nt], 0, 0, 0);
            }
        }

        // ---- online softmax in C-layout (rows quad*4+r, col nt*16+ln) ----
        const bool fullv = (j < qt);   // tile fully causal-valid for block
        float pv[4][4];
        float mt[4] = {-1e30f, -1e30f, -1e30f, -1e30f};
#pragma unroll
        for (int nt = 0; nt < 4; ++nt) {
            const bool mk = (Msk[nt * 16 + ln] != 0);
            const int kpos = j * 64 + nt * 16 + ln;
#pragma unroll
            for (int r = 0; r < 4; ++r) {
                float s = sacc[nt][r] * 0.125f;
                const bool valid =
                    mk && (fullv || kpos <= wrb + quad * 4 + r);
                s = valid ? s : -1e30f;
                pv[nt][r] = s;
                mt[r] = fmaxf(mt[r], s);
            }
        }
#pragma unroll
        for (int r = 0; r < 4; ++r) {
            mt[r] = fmaxf(mt[r], __shfl_xor(mt[r], 1));
            mt[r] = fmaxf(mt[r], __shfl_xor(mt[r], 2));
            mt[r] = fmaxf(mt[r], __shfl_xor(mt[r], 4));
            mt[r] = fmaxf(mt[r], __shfl_xor(mt[r], 8));
        }
        float alpha[4], rsum[4];
#pragma unroll
        for (int r = 0; r < 4; ++r) {
            const float mn = fmaxf(mrow[r], mt[r]);
            alpha[r] = __expf(mrow[r] - mn);
            mrow[r] = mn;
            rsum[r] = 0.f;
        }
#pragma unroll
        for (int nt = 0; nt < 4; ++nt)
#pragma unroll
            for (int r = 0; r < 4; ++r) {
                const float p = (pv[nt][r] <= -1e29f)
                                    ? 0.f
                                    : __expf(pv[nt][r] - mrow[r]);
                pv[nt][r] = p;
                rsum[r] += p;
            }
#pragma unroll
        for (int r = 0; r < 4; ++r) {
            rsum[r] += __shfl_xor(rsum[r], 1);
            rsum[r] += __shfl_xor(rsum[r], 2);
            rsum[r] += __shfl_xor(rsum[r], 4);
            rsum[r] += __shfl_xor(rsum[r], 8);
            lrow[r] = lrow[r] * alpha[r] + rsum[r];
        }
#pragma unroll
        for (int nt = 0; nt < 4; ++nt)
#pragma unroll
            for (int r = 0; r < 4; ++r) oacc[nt][r] *= alpha[r];

        // ---- P -> LDS (bf16), wave-private region ----
#pragma unroll
        for (int nt = 0; nt < 4; ++nt)
#pragma unroll
            for (int r = 0; r < 4; ++r)
                Ps[wave * 16 + quad * 4 + r][nt * 16 + ln] =
                    bf16rne(pv[nt][r]);
        // wave-private LDS round-trip: drain DS writes, keep vmcnt in flight
        asm volatile("s_waitcnt lgkmcnt(0)" ::: "memory");

        // ---- O += P V : A=P[m=ln][k], B=V^T[n=dim][k] ----
#pragma unroll
        for (int kc = 0; kc < 2; ++kc) {
            const bf16x8 pa =
                *(const bf16x8*)&Ps[wave * 16 + ln][kc * 32 + quad * 8];
#pragma unroll
            for (int nt = 0; nt < 4; ++nt) {
                const bf16x8 vb =
                    *(const bf16x8*)&Vt[nt * 16 + ln][kc * 32 + quad * 8];
                oacc[nt] = __builtin_amdgcn_mfma_f32_16x16x32_bf16(
                    pa, vb, oacc[nt], 0, 0, 0);
            }
        }
    }

    // ---- epilogue: divide by l, fp32 store ----
#pragma unroll
    for (int r = 0; r < 4; ++r) {
        const float inv = 1.0f / lrow[r];
        const size_t rowoff = ((size_t)b * Tn + wrb + quad * 4 + r) * Hn;
#pragma unroll
        for (int nt = 0; nt < 4; ++nt)
            out[rowoff + nt * 16 + ln] = oacc[nt][r] * inv;
    }
}

extern "C" void kernel_launch(void* const* d_in, const int* in_sizes, int n_in,
                              void* d_out, int out_size, void* d_ws, size_t ws_size,
                              hipStream_t stream)
{
    const float* k    = (const float*)d_in[0];
    const float* q    = (const float*)d_in[1];
    const float* v    = (const float*)d_in[2];
    const int*   mask = (const int*)d_in[3];
    const float* Wk   = (const float*)d_in[4];
    const float* Wq   = (const float*)d_in[5];
    const float* Wv   = (const float*)d_in[6];
    float* out = (float*)d_out;
    unsigned short* ws = (unsigned short*)d_ws;  // kh|qh|vh bf16, 6.3 MB

    dim3 pb(256), pg(Bn * Tn / 64, 3);
    proj_kernel<<<pg, pb, 0, stream>>>(k, q, v, Wk, Wq, Wv, ws);

    dim3 ab(256), ag(Tn / 64, Bn);
    attn_kernel<<<ag, ab, 0, stream>>>(ws, mask, out);
}